// Round 1
// baseline (1834.782 us; speedup 1.0000x reference)
//
#include <hip/hip_runtime.h>
#include <math.h>

#define C_CH 512
#define T_LEN 4096
#define B_N 4

// ---- ws float offsets ----
#define OFF_FILT 0
#define OFF_S1   64
#define OFF_S2   (OFF_S1 + 512)
#define OFF_S3   (OFF_S2 + 2048)
#define OFF_WF   4096
#define OFF_H1   (OFF_WF + 512*512)
#define OFF_H2   (OFF_H1 + 8388608)
// total ws: (OFF_H2 + 8388608) floats ~= 68.2 MB

__device__ double i0d(double x) {
  double t = 0.5 * x, t2 = t * t;
  double term = 1.0, sum = 1.0;
  for (int k = 1; k < 60; ++k) {
    term *= t2 / ((double)k * (double)k);
    sum += term;
    if (term < 1e-17 * sum) break;
  }
  return sum;
}

// blocks 0..511: scale1 ; 512..2559: scale2 ; 2560..3071: scale3 ; 3072: FIR filter
__global__ __launch_bounds__(256) void init_consts(
    const float* __restrict__ v1, const float* __restrict__ g1,
    const float* __restrict__ v2, const float* __restrict__ g2,
    const float* __restrict__ v3, const float* __restrict__ g3,
    float* __restrict__ ws)
{
  int blk = blockIdx.x;
  if (blk == 3072) {
    if (threadIdx.x == 0) {
      // kaiser_sinc_filter(0.25, 0.3, 12) in double precision
      double beta = 0.1102 * (2.285 * 5.0 * M_PI * 1.2 + 7.95 - 8.7);
      double ib = i0d(beta);
      double f[12]; double s = 0.0;
      for (int n = 0; n < 12; ++n) {
        double r = ((double)n - 5.5) / 5.5;
        double w = i0d(beta * sqrt(fmax(0.0, 1.0 - r * r))) / ib;
        double tt = ((double)n - 5.5) * 0.5;      // 2*cutoff*t, cutoff=0.25
        double sc = sin(M_PI * tt) / (M_PI * tt); // t never 0 (even kernel)
        f[n] = 0.5 * w * sc;
        s += f[n];
      }
      for (int n = 0; n < 12; ++n) ws[OFF_FILT + n] = (float)(f[n] / s);
    }
    return;
  }
  const float* v; const float* g; int len; float* out;
  if (blk < 512)       { v = v1 + (size_t)blk * 3584;        g = g1 + blk;        len = 3584; out = ws + OFF_S1 + blk; }
  else if (blk < 2560) { int m = blk - 512;  v = v2 + (size_t)m * 512;  g = g2 + m; len = 512;  out = ws + OFF_S2 + m; }
  else                 { int m = blk - 2560; v = v3 + (size_t)m * 2048; g = g3 + m; len = 2048; out = ws + OFF_S3 + m; }
  float s = 0.f;
  for (int i = threadIdx.x; i < len; i += 256) { float x = v[i]; s = fmaf(x, x, s); }
  #pragma unroll
  for (int off = 32; off > 0; off >>= 1) s += __shfl_down(s, off);
  __shared__ float red[4];
  int lane = threadIdx.x & 63, w = threadIdx.x >> 6;
  if (lane == 0) red[w] = s;
  __syncthreads();
  if (threadIdx.x == 0) {
    float tot = red[0] + red[1] + red[2] + red[3];
    *out = g[0] / sqrtf(tot);   // g / ||v||
  }
}

// wf[o][i] = s3[o] * sum_m v3[o][m] * s2[m] * v2[m][i]   (512 x 512, K=2048)
__global__ __launch_bounds__(256) void fuse_w(
    const float* __restrict__ v2, const float* __restrict__ v3,
    float* __restrict__ ws)
{
  const float* s2 = ws + OFF_S2;
  const float* s3 = ws + OFF_S3;
  float* wf = ws + OFF_WF;
  __shared__ float a[32][68];   // a[mm][o_l] from v3 (padded: conflict/alignment)
  __shared__ float bsh[32][68]; // b[mm][i_l] = s2*v2
  int i0 = blockIdx.x * 64, o0 = blockIdx.y * 64;
  int tid = threadIdx.x;
  int ii = tid & 15, io = tid >> 4;
  float acc[4][4] = {};
  for (int m0 = 0; m0 < 2048; m0 += 32) {
    for (int idx = tid; idx < 2048; idx += 256) {
      int o_l = idx >> 5, mm = idx & 31;
      a[mm][o_l] = v3[(size_t)(o0 + o_l) * 2048 + m0 + mm];
    }
    for (int idx = tid; idx < 2048; idx += 256) {
      int mm = idx >> 6, i_l = idx & 63;
      bsh[mm][i_l] = v2[(size_t)(m0 + mm) * 512 + i0 + i_l] * s2[m0 + mm];
    }
    __syncthreads();
    #pragma unroll 8
    for (int mm = 0; mm < 32; ++mm) {
      float4 av = *(const float4*)&a[mm][io * 4];
      float4 bv = *(const float4*)&bsh[mm][ii * 4];
      float ar[4] = {av.x, av.y, av.z, av.w};
      float br[4] = {bv.x, bv.y, bv.z, bv.w};
      #pragma unroll
      for (int p = 0; p < 4; ++p)
        #pragma unroll
        for (int q = 0; q < 4; ++q)
          acc[p][q] = fmaf(ar[p], br[q], acc[p][q]);
    }
    __syncthreads();
  }
  #pragma unroll
  for (int p = 0; p < 4; ++p) {
    int o = o0 + io * 4 + p;
    float sc = s3[o];
    float4 r;
    r.x = acc[p][0] * sc; r.y = acc[p][1] * sc; r.z = acc[p][2] * sc; r.w = acc[p][3] * sc;
    *(float4*)&wf[(size_t)o * 512 + i0 + ii * 4] = r;
  }
}

// fused act1d: upsample x2 (edge pad) -> snake_beta -> downsample x2 (edge pad)
// one block = one (b, c, 512-wide t chunk)
__global__ __launch_bounds__(256) void act_kernel(
    const float* __restrict__ src, float* __restrict__ dst,
    const float* __restrict__ alpha, const float* __restrict__ beta,
    const float* __restrict__ filt_g)
{
  __shared__ float xs[522];
  __shared__ float ys[1034];
  __shared__ float F[12];
  int t0 = blockIdx.x * 512;
  int c = blockIdx.y;
  int b = blockIdx.z;
  const float* row = src + ((size_t)b * C_CH + c) * T_LEN;
  float* orow = dst + ((size_t)b * C_CH + c) * T_LEN;
  int tid = threadIdx.x;
  if (tid < 12) F[tid] = filt_g[tid];
  float ea = expf(alpha[c]);
  float ibv = 1.0f / (expf(beta[c]) + 1e-9f);
  // stage x[t0-5 .. t0+516] with edge clamp
  for (int i = tid; i < 522; i += 256) {
    int g = t0 - 5 + i;
    g = min(max(g, 0), T_LEN - 1);
    xs[i] = row[g];
  }
  __syncthreads();
  // y global index n = clamp(2*t0 - 5 + m); upsample (x2, zero-stuff conv) + snake
  for (int m = tid; m < 1034; m += 256) {
    int n = 2 * t0 - 5 + m;
    n = min(max(n, 0), 2 * T_LEN - 1);
    int tp = n >> 1;
    int base = tp - t0;
    float s = 0.f;
    if (n & 1) {
      #pragma unroll
      for (int u = 0; u < 6; ++u) s = fmaf(xs[base + 3 + u], F[10 - 2 * u], s);
    } else {
      #pragma unroll
      for (int u = 0; u < 6; ++u) s = fmaf(xs[base + 2 + u], F[11 - 2 * u], s);
    }
    float y = 2.f * s;
    float sn = sinf(y * ea);
    ys[m] = fmaf(ibv * sn, sn, y);
  }
  __syncthreads();
  // downsample: h[t] = sum_k F[k] * y[clamp(2t+k-5)]  (clamp baked into ys)
  for (int tl = tid; tl < 512; tl += 256) {
    float h = 0.f;
    #pragma unroll
    for (int k = 0; k < 12; ++k) h = fmaf(F[k], ys[2 * tl + k], h);
    orow[t0 + tl] = h;
  }
}

// conv K=7, 512->512, zero pad 3, weight-norm scale at epilogue
#define IC 8
__global__ __launch_bounds__(256) void conv7(
    const float* __restrict__ h1, const float* __restrict__ v1,
    const float* __restrict__ s1, float* __restrict__ h2)
{
  __shared__ float xs[IC][72];
  __shared__ float wsh[IC][7][68];
  int t0 = blockIdx.x * 64;
  int o0 = blockIdx.y * 64;
  int b  = blockIdx.z;
  int tid = threadIdx.x;
  int tt = tid & 15;   // 16 t-groups of 4
  int oo = tid >> 4;   // 16 o-groups of 4
  float acc[4][4] = {};
  const float* xbase = h1 + (size_t)b * C_CH * T_LEN;
  for (int ic = 0; ic < C_CH; ic += IC) {
    for (int idx = tid; idx < IC * 70; idx += 256) {
      int r = idx / 70, cc = idx % 70;
      int gt = t0 - 3 + cc;
      float v = 0.f;
      if (gt >= 0 && gt < T_LEN) v = xbase[(size_t)(ic + r) * T_LEN + gt];
      xs[r][cc] = v;
    }
    for (int idx = tid; idx < IC * 7 * 64; idx += 256) {
      int o_l = idx / 56;
      int rem = idx % 56;
      int i_l = rem / 7, k = rem % 7;
      wsh[i_l][k][o_l] = v1[((size_t)(o0 + o_l) * C_CH + ic + i_l) * 7 + k];
    }
    __syncthreads();
    #pragma unroll
    for (int i = 0; i < IC; ++i) {
      float4 xa = *(const float4*)&xs[i][tt * 4];
      float4 xb = *(const float4*)&xs[i][tt * 4 + 4];
      float4 xc = *(const float4*)&xs[i][tt * 4 + 8];
      float xw[12] = {xa.x, xa.y, xa.z, xa.w, xb.x, xb.y, xb.z, xb.w, xc.x, xc.y, xc.z, xc.w};
      #pragma unroll
      for (int k = 0; k < 7; ++k) {
        float4 w4 = *(const float4*)&wsh[i][k][oo * 4];
        float wv[4] = {w4.x, w4.y, w4.z, w4.w};
        #pragma unroll
        for (int p = 0; p < 4; ++p)
          #pragma unroll
          for (int q = 0; q < 4; ++q)
            acc[p][q] = fmaf(wv[p], xw[k + q], acc[p][q]);
      }
    }
    __syncthreads();
  }
  #pragma unroll
  for (int p = 0; p < 4; ++p) {
    int o = o0 + oo * 4 + p;
    float sc = s1[o];
    float4 r;
    r.x = acc[p][0] * sc; r.y = acc[p][1] * sc; r.z = acc[p][2] * sc; r.w = acc[p][3] * sc;
    *(float4*)&h2[((size_t)b * C_CH + o) * T_LEN + t0 + tt * 4] = r;
  }
}

// out = x + wf @ h   (1x1, 512->512, wf prescaled)
__global__ __launch_bounds__(256) void gemm_res(
    const float* __restrict__ h, const float* __restrict__ wf,
    const float* __restrict__ x, float* __restrict__ out)
{
  __shared__ float xsh[16][64];
  __shared__ float wsm[16][68];
  int t0 = blockIdx.x * 64;
  int o0 = blockIdx.y * 64;
  int b  = blockIdx.z;
  int tid = threadIdx.x;
  int tt = tid & 15, oo = tid >> 4;
  float acc[4][4] = {};
  for (int ic = 0; ic < 512; ic += 16) {
    for (int idx = tid; idx < 16 * 64; idx += 256) {
      int r = idx >> 6, cc = idx & 63;
      xsh[r][cc] = h[((size_t)b * C_CH + ic + r) * T_LEN + t0 + cc];
    }
    for (int idx = tid; idx < 16 * 64; idx += 256) {
      int o_l = idx >> 4, i_l = idx & 15;
      wsm[i_l][o_l] = wf[(size_t)(o0 + o_l) * 512 + ic + i_l];
    }
    __syncthreads();
    #pragma unroll
    for (int i = 0; i < 16; ++i) {
      float4 w4 = *(const float4*)&wsm[i][oo * 4];
      float4 x4 = *(const float4*)&xsh[i][tt * 4];
      float wv[4] = {w4.x, w4.y, w4.z, w4.w};
      float xv[4] = {x4.x, x4.y, x4.z, x4.w};
      #pragma unroll
      for (int p = 0; p < 4; ++p)
        #pragma unroll
        for (int q = 0; q < 4; ++q)
          acc[p][q] = fmaf(wv[p], xv[q], acc[p][q]);
    }
    __syncthreads();
  }
  #pragma unroll
  for (int p = 0; p < 4; ++p) {
    int o = o0 + oo * 4 + p;
    size_t off = ((size_t)b * C_CH + o) * T_LEN + t0 + tt * 4;
    float4 xr = *(const float4*)&x[off];
    float4 r;
    r.x = xr.x + acc[p][0]; r.y = xr.y + acc[p][1];
    r.z = xr.z + acc[p][2]; r.w = xr.w + acc[p][3];
    *(float4*)&out[off] = r;
  }
}

extern "C" void kernel_launch(void* const* d_in, const int* in_sizes, int n_in,
                              void* d_out, int out_size, void* d_ws, size_t ws_size,
                              hipStream_t stream) {
  const float* x  = (const float*)d_in[0];
  const float* a1 = (const float*)d_in[1];
  const float* b1 = (const float*)d_in[2];
  const float* v1 = (const float*)d_in[3];
  const float* g1 = (const float*)d_in[4];
  const float* a2 = (const float*)d_in[5];
  const float* b2 = (const float*)d_in[6];
  const float* v2 = (const float*)d_in[7];
  const float* g2 = (const float*)d_in[8];
  const float* v3 = (const float*)d_in[9];
  const float* g3 = (const float*)d_in[10];
  float* out = (float*)d_out;
  float* ws  = (float*)d_ws;
  float* h1  = ws + OFF_H1;
  float* h2  = ws + OFF_H2;

  init_consts<<<3073, 256, 0, stream>>>(v1, g1, v2, g2, v3, g3, ws);
  fuse_w<<<dim3(8, 8), 256, 0, stream>>>(v2, v3, ws);
  act_kernel<<<dim3(8, 512, 4), 256, 0, stream>>>(x, h1, a1, b1, ws + OFF_FILT);
  conv7<<<dim3(64, 8, 4), 256, 0, stream>>>(h1, v1, ws + OFF_S1, h2);
  act_kernel<<<dim3(8, 512, 4), 256, 0, stream>>>(h2, h1, a2, b2, ws + OFF_FILT);
  gemm_res<<<dim3(64, 8, 4), 256, 0, stream>>>(h1, ws + OFF_WF, x, out);
}

// Round 3
// 868.201 us; speedup vs baseline: 2.1133x; 2.1133x over previous
//
#include <hip/hip_runtime.h>
#include <math.h>

#define C_CH 512
#define T_LEN 4096

typedef unsigned short bf16_t;
typedef short bf16x8 __attribute__((ext_vector_type(8)));
typedef float f32x4 __attribute__((ext_vector_type(4)));

__device__ inline bf16_t f2bf(float x) {
  unsigned u = __float_as_uint(x);
  return (bf16_t)((u + 0x7FFF + ((u >> 16) & 1)) >> 16);
}
__device__ inline float bf2f(bf16_t h) { return __uint_as_float(((unsigned)h) << 16); }
__device__ inline float loadv(const float* p, int i) { return p[i]; }
__device__ inline float loadv(const bf16_t* p, int i) { return bf2f(p[i]); }

// ---- ws float offsets ----
#define OFF_FILT 0
#define OFF_S1   64
#define OFF_S2   576
#define OFF_S3   2624
#define OFF_WF   4096                  // 512*512 f32
#define OFF_WP1  266240                // 7*512*512 bf16 = 917504 f32
#define OFF_WPF  1183744               // 512*512 bf16 = 131072 f32
#define OFF_H1   1314816               // 4*512*4096 bf16 = 4194304 f32
#define OFF_H2   5509120
#define OFF_H3   9703424
// end 13897728 floats = 55.6 MB

__device__ double i0d(double x) {
  double t = 0.5 * x, t2 = t * t;
  double term = 1.0, sum = 1.0;
  for (int k = 1; k < 60; ++k) {
    term *= t2 / ((double)k * (double)k);
    sum += term;
    if (term < 1e-17 * sum) break;
  }
  return sum;
}

__global__ __launch_bounds__(256) void init_consts(
    const float* __restrict__ v1, const float* __restrict__ g1,
    const float* __restrict__ v2, const float* __restrict__ g2,
    const float* __restrict__ v3, const float* __restrict__ g3,
    float* __restrict__ ws)
{
  int blk = blockIdx.x;
  if (blk == 3072) {
    if (threadIdx.x == 0) {
      double beta = 0.1102 * (2.285 * 5.0 * M_PI * 1.2 + 7.95 - 8.7);
      double ib = i0d(beta);
      double f[12]; double s = 0.0;
      for (int n = 0; n < 12; ++n) {
        double r = ((double)n - 5.5) / 5.5;
        double w = i0d(beta * sqrt(fmax(0.0, 1.0 - r * r))) / ib;
        double tt = ((double)n - 5.5) * 0.5;
        double sc = sin(M_PI * tt) / (M_PI * tt);
        f[n] = 0.5 * w * sc;
        s += f[n];
      }
      for (int n = 0; n < 12; ++n) ws[OFF_FILT + n] = (float)(f[n] / s);
    }
    return;
  }
  const float* v; const float* g; int len; float* out;
  if (blk < 512)       { v = v1 + (size_t)blk * 3584;        g = g1 + blk;        len = 3584; out = ws + OFF_S1 + blk; }
  else if (blk < 2560) { int m = blk - 512;  v = v2 + (size_t)m * 512;  g = g2 + m; len = 512;  out = ws + OFF_S2 + m; }
  else                 { int m = blk - 2560; v = v3 + (size_t)m * 2048; g = g3 + m; len = 2048; out = ws + OFF_S3 + m; }
  float s = 0.f;
  for (int i = threadIdx.x; i < len; i += 256) { float x = v[i]; s = fmaf(x, x, s); }
  #pragma unroll
  for (int off = 32; off > 0; off >>= 1) s += __shfl_down(s, off);
  __shared__ float red[4];
  int lane = threadIdx.x & 63, w = threadIdx.x >> 6;
  if (lane == 0) red[w] = s;
  __syncthreads();
  if (threadIdx.x == 0) {
    float tot = red[0] + red[1] + red[2] + red[3];
    *out = g[0] / sqrtf(tot);
  }
}

// wf[o][i] = s3[o] * sum_m v3[o][m] * s2[m] * v2[m][i]
__global__ __launch_bounds__(256) void fuse_w(
    const float* __restrict__ v2, const float* __restrict__ v3,
    float* __restrict__ ws)
{
  const float* s2 = ws + OFF_S2;
  const float* s3 = ws + OFF_S3;
  float* wf = ws + OFF_WF;
  __shared__ float a[32][68];
  __shared__ float bsh[32][68];
  int i0 = blockIdx.x * 64, o0 = blockIdx.y * 64;
  int tid = threadIdx.x;
  int ii = tid & 15, io = tid >> 4;
  float acc[4][4] = {};
  for (int m0 = 0; m0 < 2048; m0 += 32) {
    for (int idx = tid; idx < 2048; idx += 256) {
      int o_l = idx >> 5, mm = idx & 31;
      a[mm][o_l] = v3[(size_t)(o0 + o_l) * 2048 + m0 + mm];
    }
    for (int idx = tid; idx < 2048; idx += 256) {
      int mm = idx >> 6, i_l = idx & 63;
      bsh[mm][i_l] = v2[(size_t)(m0 + mm) * 512 + i0 + i_l] * s2[m0 + mm];
    }
    __syncthreads();
    #pragma unroll 8
    for (int mm = 0; mm < 32; ++mm) {
      float4 av = *(const float4*)&a[mm][io * 4];
      float4 bv = *(const float4*)&bsh[mm][ii * 4];
      float ar[4] = {av.x, av.y, av.z, av.w};
      float br[4] = {bv.x, bv.y, bv.z, bv.w};
      #pragma unroll
      for (int p = 0; p < 4; ++p)
        #pragma unroll
        for (int q = 0; q < 4; ++q)
          acc[p][q] = fmaf(ar[p], br[q], acc[p][q]);
    }
    __syncthreads();
  }
  #pragma unroll
  for (int p = 0; p < 4; ++p) {
    int o = o0 + io * 4 + p;
    float sc = s3[o];
    float4 r;
    r.x = acc[p][0] * sc; r.y = acc[p][1] * sc; r.z = acc[p][2] * sc; r.w = acc[p][3] * sc;
    *(float4*)&wf[(size_t)o * 512 + i0 + ii * 4] = r;
  }
}

// wp1[tap][o][i] = bf16(v1[o][i][tap] * s1[o])
__global__ __launch_bounds__(256) void wprep1(
    const float* __restrict__ v1, const float* __restrict__ s1w,
    bf16_t* __restrict__ wp)
{
  int idx = blockIdx.x * 256 + threadIdx.x;   // 7*512*512
  int i = idx & 511;
  int o = (idx >> 9) & 511;
  int tap = idx >> 18;
  wp[idx] = f2bf(v1[((size_t)o * 512 + i) * 7 + tap] * s1w[o]);
}

// wpf[o][i] = bf16(wf[o][i])
__global__ __launch_bounds__(256) void wfpack(
    const float* __restrict__ wf, bf16_t* __restrict__ wpf)
{
  int idx = blockIdx.x * 256 + threadIdx.x;   // 512*512
  wpf[idx] = f2bf(wf[idx]);
}

// fused act1d: upsample x2 (edge pad) -> snake_beta -> downsample x2
template <typename T>
__global__ __launch_bounds__(256) void act_kernel(
    const T* __restrict__ src, bf16_t* __restrict__ dst,
    const float* __restrict__ alpha, const float* __restrict__ beta,
    const float* __restrict__ filt_g)
{
  __shared__ float xs[522];
  __shared__ float ys[1034];
  __shared__ float F[12];
  int t0 = blockIdx.x * 512;
  int c = blockIdx.y;
  int b = blockIdx.z;
  const T* row = src + ((size_t)b * C_CH + c) * T_LEN;
  bf16_t* orow = dst + ((size_t)b * C_CH + c) * T_LEN;
  int tid = threadIdx.x;
  if (tid < 12) F[tid] = filt_g[tid];
  float ea = expf(alpha[c]);
  float ibv = 1.0f / (expf(beta[c]) + 1e-9f);
  for (int i = tid; i < 522; i += 256) {
    int g = t0 - 5 + i;
    g = min(max(g, 0), T_LEN - 1);
    xs[i] = loadv(row, g);
  }
  __syncthreads();
  for (int m = tid; m < 1034; m += 256) {
    int n = 2 * t0 - 5 + m;
    n = min(max(n, 0), 2 * T_LEN - 1);
    int tp = n >> 1;
    int base = tp - t0;
    float s = 0.f;
    if (n & 1) {
      #pragma unroll
      for (int u = 0; u < 6; ++u) s = fmaf(xs[base + 3 + u], F[10 - 2 * u], s);
    } else {
      #pragma unroll
      for (int u = 0; u < 6; ++u) s = fmaf(xs[base + 2 + u], F[11 - 2 * u], s);
    }
    float y = 2.f * s;
    float sn = sinf(y * ea);
    ys[m] = fmaf(ibv * sn, sn, y);
  }
  __syncthreads();
  for (int tl = tid; tl < 512; tl += 256) {
    float h = 0.f;
    #pragma unroll
    for (int k = 0; k < 12; ++k) h = fmaf(F[k], ys[2 * tl + k], h);
    orow[t0 + tl] = f2bf(h);
  }
}

// conv K=7, 512->512, zero-pad-3, MFMA 16x16x32 bf16.
// Block: 128 threads (2 waves). Block tile 128(o) x 128(t). Wave: 64(o)x128(t), m4 x n8 frags.
// LDS: X^T tile [144 rows(t)][64 ch], 128B pitch, byte ^= (row&7)<<4 swizzle.
__global__ __launch_bounds__(128, 2) void conv7_mfma(
    const bf16_t* __restrict__ src, const bf16_t* __restrict__ wp,
    bf16_t* __restrict__ dst)
{
  __shared__ __align__(16) bf16_t Xs[144 * 64];
  const int t0 = blockIdx.x * 128;
  const int o0 = blockIdx.y * 128;
  const int b  = blockIdx.z;
  const int tid = threadIdx.x;
  const int wave = tid >> 6;
  const int lane = tid & 63;
  const int l15 = lane & 15, lhi = lane >> 4;   // lhi in [0,4)
  f32x4 acc[4][8];
  #pragma unroll
  for (int m = 0; m < 4; ++m)
    #pragma unroll
    for (int n = 0; n < 8; ++n)
      acc[m][n] = (f32x4){0.f, 0.f, 0.f, 0.f};

  const bf16_t* xg = src + (size_t)b * C_CH * T_LEN;

  for (int cb = 0; cb < 512; cb += 64) {
    // stage rows [t0-8, t0+136) x 64 ch, transposed, swizzled
    for (int u = tid; u < 18 * 64; u += 128) {
      int cc = u & 63;
      int ro = u >> 6;                 // octet row group
      int gt0 = t0 - 8 + ro * 8;
      const bf16_t* gp = xg + (size_t)(cb + cc) * T_LEN + gt0;
      bf16_t vals[8];
      if (gt0 >= 0 && gt0 + 8 <= T_LEN) {
        bf16x8 v = *(const bf16x8*)gp;
        #pragma unroll
        for (int i = 0; i < 8; ++i) vals[i] = (bf16_t)v[i];
      } else {
        #pragma unroll
        for (int i = 0; i < 8; ++i) {
          int gt = gt0 + i;
          vals[i] = (gt >= 0 && gt < T_LEN) ? gp[i] : (bf16_t)0;
        }
      }
      #pragma unroll
      for (int i = 0; i < 8; ++i) {
        int rl = ro * 8 + i;
        int byteoff = rl * 128 + ((cc * 2) ^ ((rl & 7) << 4));
        *(bf16_t*)((char*)Xs + byteoff) = vals[i];
      }
    }
    __syncthreads();
    #pragma unroll
    for (int tap = 0; tap < 7; ++tap) {
      #pragma unroll
      for (int ks = 0; ks < 2; ++ks) {
        const int chcol = ks * 32 + lhi * 8;     // 8 contiguous channels (K block)
        bf16x8 a[4];
        #pragma unroll
        for (int m = 0; m < 4; ++m) {
          int o = o0 + wave * 64 + m * 16 + l15;
          a[m] = *(const bf16x8*)(wp + ((size_t)(tap * 512 + o) * 512) + cb + chcol);
        }
        bf16x8 bfr[8];
        #pragma unroll
        for (int n = 0; n < 8; ++n) {
          int row = n * 16 + l15 + tap + 5;
          int byteoff = row * 128 + ((chcol * 2) ^ ((row & 7) << 4));
          bfr[n] = *(const bf16x8*)((const char*)Xs + byteoff);
        }
        #pragma unroll
        for (int m = 0; m < 4; ++m)
          #pragma unroll
          for (int n = 0; n < 8; ++n)
            acc[m][n] = __builtin_amdgcn_mfma_f32_16x16x32_bf16(a[m], bfr[n], acc[m][n], 0, 0, 0);
      }
    }
    __syncthreads();
  }
  bf16_t* drow = dst + (size_t)b * C_CH * T_LEN;
  #pragma unroll
  for (int m = 0; m < 4; ++m)
    #pragma unroll
    for (int n = 0; n < 8; ++n) {
      int t = t0 + n * 16 + l15;
      #pragma unroll
      for (int r = 0; r < 4; ++r) {
        int o = o0 + wave * 64 + m * 16 + lhi * 4 + r;
        drow[(size_t)o * T_LEN + t] = f2bf(acc[m][n][r]);
      }
    }
}

// out = x + wf @ h (1x1 512->512), MFMA 16x16x32 bf16, residual f32 out
__global__ __launch_bounds__(128, 2) void gemm_mfma(
    const bf16_t* __restrict__ src, const bf16_t* __restrict__ wp,
    const float* __restrict__ x, float* __restrict__ out)
{
  __shared__ __align__(16) bf16_t Xs[128 * 64];
  const int t0 = blockIdx.x * 128;
  const int o0 = blockIdx.y * 128;
  const int b  = blockIdx.z;
  const int tid = threadIdx.x;
  const int wave = tid >> 6;
  const int lane = tid & 63;
  const int l15 = lane & 15, lhi = lane >> 4;
  f32x4 acc[4][8];
  #pragma unroll
  for (int m = 0; m < 4; ++m)
    #pragma unroll
    for (int n = 0; n < 8; ++n)
      acc[m][n] = (f32x4){0.f, 0.f, 0.f, 0.f};

  const bf16_t* xg = src + (size_t)b * C_CH * T_LEN;

  for (int cb = 0; cb < 512; cb += 64) {
    for (int u = tid; u < 16 * 64; u += 128) {
      int cc = u & 63;
      int ro = u >> 6;
      const bf16_t* gp = xg + (size_t)(cb + cc) * T_LEN + t0 + ro * 8;
      bf16x8 v = *(const bf16x8*)gp;
      #pragma unroll
      for (int i = 0; i < 8; ++i) {
        int rl = ro * 8 + i;
        int byteoff = rl * 128 + ((cc * 2) ^ ((rl & 7) << 4));
        *(bf16_t*)((char*)Xs + byteoff) = (bf16_t)v[i];
      }
    }
    __syncthreads();
    #pragma unroll
    for (int ks = 0; ks < 2; ++ks) {
      const int chcol = ks * 32 + lhi * 8;
      bf16x8 a[4];
      #pragma unroll
      for (int m = 0; m < 4; ++m) {
        int o = o0 + wave * 64 + m * 16 + l15;
        a[m] = *(const bf16x8*)(wp + (size_t)o * 512 + cb + chcol);
      }
      bf16x8 bfr[8];
      #pragma unroll
      for (int n = 0; n < 8; ++n) {
        int row = n * 16 + l15;
        int byteoff = row * 128 + ((chcol * 2) ^ ((row & 7) << 4));
        bfr[n] = *(const bf16x8*)((const char*)Xs + byteoff);
      }
      #pragma unroll
      for (int m = 0; m < 4; ++m)
        #pragma unroll
        for (int n = 0; n < 8; ++n)
          acc[m][n] = __builtin_amdgcn_mfma_f32_16x16x32_bf16(a[m], bfr[n], acc[m][n], 0, 0, 0);
    }
    __syncthreads();
  }
  #pragma unroll
  for (int m = 0; m < 4; ++m)
    #pragma unroll
    for (int n = 0; n < 8; ++n) {
      int t = t0 + n * 16 + l15;
      #pragma unroll
      for (int r = 0; r < 4; ++r) {
        int o = o0 + wave * 64 + m * 16 + lhi * 4 + r;
        size_t off = ((size_t)b * C_CH + o) * T_LEN + t;
        out[off] = x[off] + acc[m][n][r];
      }
    }
}

extern "C" void kernel_launch(void* const* d_in, const int* in_sizes, int n_in,
                              void* d_out, int out_size, void* d_ws, size_t ws_size,
                              hipStream_t stream) {
  const float* x  = (const float*)d_in[0];
  const float* a1 = (const float*)d_in[1];
  const float* b1 = (const float*)d_in[2];
  const float* v1 = (const float*)d_in[3];
  const float* g1 = (const float*)d_in[4];
  const float* a2 = (const float*)d_in[5];
  const float* b2 = (const float*)d_in[6];
  const float* v2 = (const float*)d_in[7];
  const float* g2 = (const float*)d_in[8];
  const float* v3 = (const float*)d_in[9];
  const float* g3 = (const float*)d_in[10];
  float* out = (float*)d_out;
  float* ws  = (float*)d_ws;
  bf16_t* wp1 = (bf16_t*)(ws + OFF_WP1);
  bf16_t* wpf = (bf16_t*)(ws + OFF_WPF);
  bf16_t* h1  = (bf16_t*)(ws + OFF_H1);
  bf16_t* h2  = (bf16_t*)(ws + OFF_H2);
  bf16_t* h3  = (bf16_t*)(ws + OFF_H3);

  init_consts<<<3073, 256, 0, stream>>>(v1, g1, v2, g2, v3, g3, ws);
  fuse_w<<<dim3(8, 8), 256, 0, stream>>>(v2, v3, ws);
  wprep1<<<7168, 256, 0, stream>>>(v1, ws + OFF_S1, wp1);
  wfpack<<<1024, 256, 0, stream>>>(ws + OFF_WF, wpf);
  act_kernel<float><<<dim3(8, 512, 4), 256, 0, stream>>>(x, h1, a1, b1, ws + OFF_FILT);
  conv7_mfma<<<dim3(32, 4, 4), 128, 0, stream>>>(h1, wp1, h2);
  act_kernel<bf16_t><<<dim3(8, 512, 4), 256, 0, stream>>>(h2, h3, a2, b2, ws + OFF_FILT);
  gemm_mfma<<<dim3(32, 4, 4), 128, 0, stream>>>(h3, wpf, x, out);
}

// Round 4
// 553.516 us; speedup vs baseline: 3.3148x; 1.5685x over previous
//
#include <hip/hip_runtime.h>
#include <math.h>

#define C_CH 512
#define T_LEN 4096

typedef unsigned short bf16_t;
typedef short bf16x8 __attribute__((ext_vector_type(8)));
typedef float f32x4 __attribute__((ext_vector_type(4)));

__device__ inline bf16_t f2bf(float x) {
  unsigned u = __float_as_uint(x);
  return (bf16_t)((u + 0x7FFF + ((u >> 16) & 1)) >> 16);
}
__device__ inline float bf2f(bf16_t h) { return __uint_as_float(((unsigned)h) << 16); }
__device__ inline float loadv(const float* p, int i) { return p[i]; }
__device__ inline float loadv(const bf16_t* p, int i) { return bf2f(p[i]); }

// ---- ws float offsets ----
#define OFF_FILT 0
#define OFF_S1   64
#define OFF_S2   576
#define OFF_S3   2624
#define OFF_WFP  4096                  // 8 * 512*512 f32 partials = 2097152 f32
#define OFF_WP1  2101248               // 7*512*512 bf16 = 917504 f32
#define OFF_WPF  3018752               // 512*512 bf16 = 131072 f32
#define OFF_H1   3149824               // 4*512*4096 bf16 = 4194304 f32
#define OFF_H2   7344128
#define OFF_H3   11538432
// end 15732736 floats = 62.9 MB

__device__ double i0d(double x) {
  double t = 0.5 * x, t2 = t * t;
  double term = 1.0, sum = 1.0;
  for (int k = 1; k < 60; ++k) {
    term *= t2 / ((double)k * (double)k);
    sum += term;
    if (term < 1e-17 * sum) break;
  }
  return sum;
}

__global__ __launch_bounds__(256) void init_consts(
    const float* __restrict__ v1, const float* __restrict__ g1,
    const float* __restrict__ v2, const float* __restrict__ g2,
    const float* __restrict__ v3, const float* __restrict__ g3,
    float* __restrict__ ws)
{
  int blk = blockIdx.x;
  if (blk == 3072) {
    if (threadIdx.x == 0) {
      double beta = 0.1102 * (2.285 * 5.0 * M_PI * 1.2 + 7.95 - 8.7);
      double ib = i0d(beta);
      double f[12]; double s = 0.0;
      for (int n = 0; n < 12; ++n) {
        double r = ((double)n - 5.5) / 5.5;
        double w = i0d(beta * sqrt(fmax(0.0, 1.0 - r * r))) / ib;
        double tt = ((double)n - 5.5) * 0.5;
        double sc = sin(M_PI * tt) / (M_PI * tt);
        f[n] = 0.5 * w * sc;
        s += f[n];
      }
      for (int n = 0; n < 12; ++n) ws[OFF_FILT + n] = (float)(f[n] / s);
    }
    return;
  }
  const float* v; const float* g; int len; float* out;
  if (blk < 512)       { v = v1 + (size_t)blk * 3584;        g = g1 + blk;        len = 3584; out = ws + OFF_S1 + blk; }
  else if (blk < 2560) { int m = blk - 512;  v = v2 + (size_t)m * 512;  g = g2 + m; len = 512;  out = ws + OFF_S2 + m; }
  else                 { int m = blk - 2560; v = v3 + (size_t)m * 2048; g = g3 + m; len = 2048; out = ws + OFF_S3 + m; }
  float s = 0.f;
  for (int i = threadIdx.x; i < len; i += 256) { float x = v[i]; s = fmaf(x, x, s); }
  #pragma unroll
  for (int off = 32; off > 0; off >>= 1) s += __shfl_down(s, off);
  __shared__ float red[4];
  int lane = threadIdx.x & 63, w = threadIdx.x >> 6;
  if (lane == 0) red[w] = s;
  __syncthreads();
  if (threadIdx.x == 0) {
    float tot = red[0] + red[1] + red[2] + red[3];
    *out = g[0] / sqrtf(tot);
  }
}

// split-K: wfp[kc][o][i] = sum_{m in chunk kc} v3[o][m] * s2[m] * v2[m][i]
__global__ __launch_bounds__(256) void fuse_w(
    const float* __restrict__ v2, const float* __restrict__ v3,
    float* __restrict__ ws)
{
  const float* s2 = ws + OFF_S2;
  float* wfp = ws + OFF_WFP;
  __shared__ float a[32][68];
  __shared__ float bsh[32][68];
  int i0 = blockIdx.x * 64, o0 = blockIdx.y * 64;
  int mbase = blockIdx.z * 256;
  int tid = threadIdx.x;
  int ii = tid & 15, io = tid >> 4;
  float acc[4][4] = {};
  for (int m0 = mbase; m0 < mbase + 256; m0 += 32) {
    for (int idx = tid; idx < 2048; idx += 256) {
      int o_l = idx >> 5, mm = idx & 31;
      a[mm][o_l] = v3[(size_t)(o0 + o_l) * 2048 + m0 + mm];
    }
    for (int idx = tid; idx < 2048; idx += 256) {
      int mm = idx >> 6, i_l = idx & 63;
      bsh[mm][i_l] = v2[(size_t)(m0 + mm) * 512 + i0 + i_l] * s2[m0 + mm];
    }
    __syncthreads();
    #pragma unroll 8
    for (int mm = 0; mm < 32; ++mm) {
      float4 av = *(const float4*)&a[mm][io * 4];
      float4 bv = *(const float4*)&bsh[mm][ii * 4];
      float ar[4] = {av.x, av.y, av.z, av.w};
      float br[4] = {bv.x, bv.y, bv.z, bv.w};
      #pragma unroll
      for (int p = 0; p < 4; ++p)
        #pragma unroll
        for (int q = 0; q < 4; ++q)
          acc[p][q] = fmaf(ar[p], br[q], acc[p][q]);
    }
    __syncthreads();
  }
  float* wout = wfp + (size_t)blockIdx.z * 512 * 512;
  #pragma unroll
  for (int p = 0; p < 4; ++p) {
    int o = o0 + io * 4 + p;
    float4 r;
    r.x = acc[p][0]; r.y = acc[p][1]; r.z = acc[p][2]; r.w = acc[p][3];
    *(float4*)&wout[(size_t)o * 512 + i0 + ii * 4] = r;
  }
}

// reduce 8 partials, scale by s3, emit bf16: wpf[o][i]
__global__ __launch_bounds__(256) void wfpack(
    const float* __restrict__ wfp, const float* __restrict__ s3,
    bf16_t* __restrict__ wpf)
{
  int idx = blockIdx.x * 256 + threadIdx.x;   // 512*512
  int o = idx >> 9;
  float s = 0.f;
  #pragma unroll
  for (int kc = 0; kc < 8; ++kc) s += wfp[(size_t)kc * 262144 + idx];
  wpf[idx] = f2bf(s * s3[o]);
}

// wp1[tap][o][i] = bf16(v1[o][i][tap] * s1[o])
__global__ __launch_bounds__(256) void wprep1(
    const float* __restrict__ v1, const float* __restrict__ s1w,
    bf16_t* __restrict__ wp)
{
  int idx = blockIdx.x * 256 + threadIdx.x;   // 7*512*512
  int i = idx & 511;
  int o = (idx >> 9) & 511;
  int tap = idx >> 18;
  wp[idx] = f2bf(v1[((size_t)o * 512 + i) * 7 + tap] * s1w[o]);
}

// fused act1d: upsample x2 (edge pad) -> snake_beta -> downsample x2
template <typename T>
__global__ __launch_bounds__(256) void act_kernel(
    const T* __restrict__ src, bf16_t* __restrict__ dst,
    const float* __restrict__ alpha, const float* __restrict__ beta,
    const float* __restrict__ filt_g)
{
  __shared__ float xs[522];
  __shared__ float ys[1034];
  __shared__ float F[12];
  int t0 = blockIdx.x * 512;
  int c = blockIdx.y;
  int b = blockIdx.z;
  const T* row = src + ((size_t)b * C_CH + c) * T_LEN;
  bf16_t* orow = dst + ((size_t)b * C_CH + c) * T_LEN;
  int tid = threadIdx.x;
  if (tid < 12) F[tid] = filt_g[tid];
  float ea = expf(alpha[c]);
  float ibv = 1.0f / (expf(beta[c]) + 1e-9f);
  for (int i = tid; i < 522; i += 256) {
    int g = t0 - 5 + i;
    g = min(max(g, 0), T_LEN - 1);
    xs[i] = loadv(row, g);
  }
  __syncthreads();
  for (int m = tid; m < 1034; m += 256) {
    int n = 2 * t0 - 5 + m;
    n = min(max(n, 0), 2 * T_LEN - 1);
    int tp = n >> 1;
    int base = tp - t0;
    float s = 0.f;
    if (n & 1) {
      #pragma unroll
      for (int u = 0; u < 6; ++u) s = fmaf(xs[base + 3 + u], F[10 - 2 * u], s);
    } else {
      #pragma unroll
      for (int u = 0; u < 6; ++u) s = fmaf(xs[base + 2 + u], F[11 - 2 * u], s);
    }
    float y = 2.f * s;
    float sn = sinf(y * ea);
    ys[m] = fmaf(ibv * sn, sn, y);
  }
  __syncthreads();
  for (int tl = tid; tl < 512; tl += 256) {
    float h = 0.f;
    #pragma unroll
    for (int k = 0; k < 12; ++k) h = fmaf(F[k], ys[2 * tl + k], h);
    orow[t0 + tl] = f2bf(h);
  }
}

// conv K=7, 512->512, zero-pad-3, MFMA 16x16x32 bf16.
__global__ __launch_bounds__(128, 2) void conv7_mfma(
    const bf16_t* __restrict__ src, const bf16_t* __restrict__ wp,
    bf16_t* __restrict__ dst)
{
  __shared__ __align__(16) bf16_t Xs[144 * 64];
  const int t0 = blockIdx.x * 128;
  const int o0 = blockIdx.y * 128;
  const int b  = blockIdx.z;
  const int tid = threadIdx.x;
  const int wave = tid >> 6;
  const int lane = tid & 63;
  const int l15 = lane & 15, lhi = lane >> 4;
  f32x4 acc[4][8];
  #pragma unroll
  for (int m = 0; m < 4; ++m)
    #pragma unroll
    for (int n = 0; n < 8; ++n)
      acc[m][n] = (f32x4){0.f, 0.f, 0.f, 0.f};

  const bf16_t* xg = src + (size_t)b * C_CH * T_LEN;

  for (int cb = 0; cb < 512; cb += 64) {
    for (int u = tid; u < 18 * 64; u += 128) {
      int cc = u & 63;
      int ro = u >> 6;
      int gt0 = t0 - 8 + ro * 8;
      const bf16_t* gp = xg + (size_t)(cb + cc) * T_LEN + gt0;
      bf16_t vals[8];
      if (gt0 >= 0 && gt0 + 8 <= T_LEN) {
        bf16x8 v = *(const bf16x8*)gp;
        #pragma unroll
        for (int i = 0; i < 8; ++i) vals[i] = (bf16_t)v[i];
      } else {
        #pragma unroll
        for (int i = 0; i < 8; ++i) {
          int gt = gt0 + i;
          vals[i] = (gt >= 0 && gt < T_LEN) ? gp[i] : (bf16_t)0;
        }
      }
      #pragma unroll
      for (int i = 0; i < 8; ++i) {
        int rl = ro * 8 + i;
        int byteoff = rl * 128 + ((cc * 2) ^ ((rl & 7) << 4));
        *(bf16_t*)((char*)Xs + byteoff) = vals[i];
      }
    }
    __syncthreads();
    #pragma unroll
    for (int tap = 0; tap < 7; ++tap) {
      #pragma unroll
      for (int ks = 0; ks < 2; ++ks) {
        const int chcol = ks * 32 + lhi * 8;
        bf16x8 a[4];
        #pragma unroll
        for (int m = 0; m < 4; ++m) {
          int o = o0 + wave * 64 + m * 16 + l15;
          a[m] = *(const bf16x8*)(wp + ((size_t)(tap * 512 + o) * 512) + cb + chcol);
        }
        bf16x8 bfr[8];
        #pragma unroll
        for (int n = 0; n < 8; ++n) {
          int row = n * 16 + l15 + tap + 5;
          int byteoff = row * 128 + ((chcol * 2) ^ ((row & 7) << 4));
          bfr[n] = *(const bf16x8*)((const char*)Xs + byteoff);
        }
        #pragma unroll
        for (int m = 0; m < 4; ++m)
          #pragma unroll
          for (int n = 0; n < 8; ++n)
            acc[m][n] = __builtin_amdgcn_mfma_f32_16x16x32_bf16(a[m], bfr[n], acc[m][n], 0, 0, 0);
      }
    }
    __syncthreads();
  }
  bf16_t* drow = dst + (size_t)b * C_CH * T_LEN;
  #pragma unroll
  for (int m = 0; m < 4; ++m)
    #pragma unroll
    for (int n = 0; n < 8; ++n) {
      int t = t0 + n * 16 + l15;
      #pragma unroll
      for (int r = 0; r < 4; ++r) {
        int o = o0 + wave * 64 + m * 16 + lhi * 4 + r;
        drow[(size_t)o * T_LEN + t] = f2bf(acc[m][n][r]);
      }
    }
}

// out = x + wf @ h (1x1 512->512), MFMA 16x16x32 bf16, residual f32 out
__global__ __launch_bounds__(128, 2) void gemm_mfma(
    const bf16_t* __restrict__ src, const bf16_t* __restrict__ wp,
    const float* __restrict__ x, float* __restrict__ out)
{
  __shared__ __align__(16) bf16_t Xs[128 * 64];
  const int t0 = blockIdx.x * 128;
  const int o0 = blockIdx.y * 128;
  const int b  = blockIdx.z;
  const int tid = threadIdx.x;
  const int wave = tid >> 6;
  const int lane = tid & 63;
  const int l15 = lane & 15, lhi = lane >> 4;
  f32x4 acc[4][8];
  #pragma unroll
  for (int m = 0; m < 4; ++m)
    #pragma unroll
    for (int n = 0; n < 8; ++n)
      acc[m][n] = (f32x4){0.f, 0.f, 0.f, 0.f};

  const bf16_t* xg = src + (size_t)b * C_CH * T_LEN;

  for (int cb = 0; cb < 512; cb += 64) {
    for (int u = tid; u < 16 * 64; u += 128) {
      int cc = u & 63;
      int ro = u >> 6;
      const bf16_t* gp = xg + (size_t)(cb + cc) * T_LEN + t0 + ro * 8;
      bf16x8 v = *(const bf16x8*)gp;
      #pragma unroll
      for (int i = 0; i < 8; ++i) {
        int rl = ro * 8 + i;
        int byteoff = rl * 128 + ((cc * 2) ^ ((rl & 7) << 4));
        *(bf16_t*)((char*)Xs + byteoff) = (bf16_t)v[i];
      }
    }
    __syncthreads();
    #pragma unroll
    for (int ks = 0; ks < 2; ++ks) {
      const int chcol = ks * 32 + lhi * 8;
      bf16x8 a[4];
      #pragma unroll
      for (int m = 0; m < 4; ++m) {
        int o = o0 + wave * 64 + m * 16 + l15;
        a[m] = *(const bf16x8*)(wp + (size_t)o * 512 + cb + chcol);
      }
      bf16x8 bfr[8];
      #pragma unroll
      for (int n = 0; n < 8; ++n) {
        int row = n * 16 + l15;
        int byteoff = row * 128 + ((chcol * 2) ^ ((row & 7) << 4));
        bfr[n] = *(const bf16x8*)((const char*)Xs + byteoff);
      }
      #pragma unroll
      for (int m = 0; m < 4; ++m)
        #pragma unroll
        for (int n = 0; n < 8; ++n)
          acc[m][n] = __builtin_amdgcn_mfma_f32_16x16x32_bf16(a[m], bfr[n], acc[m][n], 0, 0, 0);
    }
    __syncthreads();
  }
  #pragma unroll
  for (int m = 0; m < 4; ++m)
    #pragma unroll
    for (int n = 0; n < 8; ++n) {
      int t = t0 + n * 16 + l15;
      #pragma unroll
      for (int r = 0; r < 4; ++r) {
        int o = o0 + wave * 64 + m * 16 + lhi * 4 + r;
        size_t off = ((size_t)b * C_CH + o) * T_LEN + t;
        out[off] = x[off] + acc[m][n][r];
      }
    }
}

extern "C" void kernel_launch(void* const* d_in, const int* in_sizes, int n_in,
                              void* d_out, int out_size, void* d_ws, size_t ws_size,
                              hipStream_t stream) {
  const float* x  = (const float*)d_in[0];
  const float* a1 = (const float*)d_in[1];
  const float* b1 = (const float*)d_in[2];
  const float* v1 = (const float*)d_in[3];
  const float* g1 = (const float*)d_in[4];
  const float* a2 = (const float*)d_in[5];
  const float* b2 = (const float*)d_in[6];
  const float* v2 = (const float*)d_in[7];
  const float* g2 = (const float*)d_in[8];
  const float* v3 = (const float*)d_in[9];
  const float* g3 = (const float*)d_in[10];
  float* out = (float*)d_out;
  float* ws  = (float*)d_ws;
  bf16_t* wp1 = (bf16_t*)(ws + OFF_WP1);
  bf16_t* wpf = (bf16_t*)(ws + OFF_WPF);
  bf16_t* h1  = (bf16_t*)(ws + OFF_H1);
  bf16_t* h2  = (bf16_t*)(ws + OFF_H2);
  bf16_t* h3  = (bf16_t*)(ws + OFF_H3);

  init_consts<<<3073, 256, 0, stream>>>(v1, g1, v2, g2, v3, g3, ws);
  fuse_w<<<dim3(8, 8, 8), 256, 0, stream>>>(v2, v3, ws);
  wfpack<<<1024, 256, 0, stream>>>(ws + OFF_WFP, ws + OFF_S3, wpf);
  wprep1<<<7168, 256, 0, stream>>>(v1, ws + OFF_S1, wp1);
  act_kernel<float><<<dim3(8, 512, 4), 256, 0, stream>>>(x, h1, a1, b1, ws + OFF_FILT);
  conv7_mfma<<<dim3(32, 4, 4), 128, 0, stream>>>(h1, wp1, h2);
  act_kernel<bf16_t><<<dim3(8, 512, 4), 256, 0, stream>>>(h2, h3, a2, b2, ws + OFF_FILT);
  gemm_mfma<<<dim3(32, 4, 4), 128, 0, stream>>>(h3, wpf, x, out);
}

// Round 5
// 394.300 us; speedup vs baseline: 4.6533x; 1.4038x over previous
//
#include <hip/hip_runtime.h>
#include <math.h>

#define C_CH 512
#define T_LEN 4096

typedef unsigned short bf16_t;
typedef short bf16x8 __attribute__((ext_vector_type(8)));
typedef float f32x4 __attribute__((ext_vector_type(4)));

__device__ inline bf16_t f2bf(float x) {
  unsigned u = __float_as_uint(x);
  return (bf16_t)((u + 0x7FFF + ((u >> 16) & 1)) >> 16);
}
__device__ inline float bf2f(bf16_t h) { return __uint_as_float(((unsigned)h) << 16); }
__device__ inline float loadv(const float* p, int i) { return p[i]; }
__device__ inline float loadv(const bf16_t* p, int i) { return bf2f(p[i]); }

// ---- ws float offsets ----
#define OFF_FILT 0
#define OFF_S1   64
#define OFF_S2   576
#define OFF_S3   2624
#define OFF_WFP  4096                  // 8 * 512*512 f32 partials
#define OFF_WP1  2101248               // 7*512*512 bf16
#define OFF_WPF  3018752               // 512*512 bf16
#define OFF_H1   3149824               // 4*512*4096 bf16
#define OFF_H2   7344128
#define OFF_H3   11538432

__device__ double i0d(double x) {
  double t = 0.5 * x, t2 = t * t;
  double term = 1.0, sum = 1.0;
  for (int k = 1; k < 60; ++k) {
    term *= t2 / ((double)k * (double)k);
    sum += term;
    if (term < 1e-17 * sum) break;
  }
  return sum;
}

__global__ __launch_bounds__(256) void init_consts(
    const float* __restrict__ v1, const float* __restrict__ g1,
    const float* __restrict__ v2, const float* __restrict__ g2,
    const float* __restrict__ v3, const float* __restrict__ g3,
    float* __restrict__ ws)
{
  int blk = blockIdx.x;
  if (blk == 3072) {
    if (threadIdx.x == 0) {
      double beta = 0.1102 * (2.285 * 5.0 * M_PI * 1.2 + 7.95 - 8.7);
      double ib = i0d(beta);
      double f[12]; double s = 0.0;
      for (int n = 0; n < 12; ++n) {
        double r = ((double)n - 5.5) / 5.5;
        double w = i0d(beta * sqrt(fmax(0.0, 1.0 - r * r))) / ib;
        double tt = ((double)n - 5.5) * 0.5;
        double sc = sin(M_PI * tt) / (M_PI * tt);
        f[n] = 0.5 * w * sc;
        s += f[n];
      }
      for (int n = 0; n < 12; ++n) ws[OFF_FILT + n] = (float)(f[n] / s);
    }
    return;
  }
  const float* v; const float* g; int len; float* out;
  if (blk < 512)       { v = v1 + (size_t)blk * 3584;        g = g1 + blk;        len = 3584; out = ws + OFF_S1 + blk; }
  else if (blk < 2560) { int m = blk - 512;  v = v2 + (size_t)m * 512;  g = g2 + m; len = 512;  out = ws + OFF_S2 + m; }
  else                 { int m = blk - 2560; v = v3 + (size_t)m * 2048; g = g3 + m; len = 2048; out = ws + OFF_S3 + m; }
  float s = 0.f;
  for (int i = threadIdx.x; i < len; i += 256) { float x = v[i]; s = fmaf(x, x, s); }
  #pragma unroll
  for (int off = 32; off > 0; off >>= 1) s += __shfl_down(s, off);
  __shared__ float red[4];
  int lane = threadIdx.x & 63, w = threadIdx.x >> 6;
  if (lane == 0) red[w] = s;
  __syncthreads();
  if (threadIdx.x == 0) {
    float tot = red[0] + red[1] + red[2] + red[3];
    *out = g[0] / sqrtf(tot);
  }
}

// split-K: wfp[kc][o][i] = sum_{m in chunk kc} v3[o][m] * s2[m] * v2[m][i]
__global__ __launch_bounds__(256) void fuse_w(
    const float* __restrict__ v2, const float* __restrict__ v3,
    float* __restrict__ ws)
{
  const float* s2 = ws + OFF_S2;
  float* wfp = ws + OFF_WFP;
  __shared__ float a[32][68];
  __shared__ float bsh[32][68];
  int i0 = blockIdx.x * 64, o0 = blockIdx.y * 64;
  int mbase = blockIdx.z * 256;
  int tid = threadIdx.x;
  int ii = tid & 15, io = tid >> 4;
  float acc[4][4] = {};
  for (int m0 = mbase; m0 < mbase + 256; m0 += 32) {
    for (int idx = tid; idx < 2048; idx += 256) {
      int o_l = idx >> 5, mm = idx & 31;
      a[mm][o_l] = v3[(size_t)(o0 + o_l) * 2048 + m0 + mm];
    }
    for (int idx = tid; idx < 2048; idx += 256) {
      int mm = idx >> 6, i_l = idx & 63;
      bsh[mm][i_l] = v2[(size_t)(m0 + mm) * 512 + i0 + i_l] * s2[m0 + mm];
    }
    __syncthreads();
    #pragma unroll 8
    for (int mm = 0; mm < 32; ++mm) {
      float4 av = *(const float4*)&a[mm][io * 4];
      float4 bv = *(const float4*)&bsh[mm][ii * 4];
      float ar[4] = {av.x, av.y, av.z, av.w};
      float br[4] = {bv.x, bv.y, bv.z, bv.w};
      #pragma unroll
      for (int p = 0; p < 4; ++p)
        #pragma unroll
        for (int q = 0; q < 4; ++q)
          acc[p][q] = fmaf(ar[p], br[q], acc[p][q]);
    }
    __syncthreads();
  }
  float* wout = wfp + (size_t)blockIdx.z * 512 * 512;
  #pragma unroll
  for (int p = 0; p < 4; ++p) {
    int o = o0 + io * 4 + p;
    float4 r;
    r.x = acc[p][0]; r.y = acc[p][1]; r.z = acc[p][2]; r.w = acc[p][3];
    *(float4*)&wout[(size_t)o * 512 + i0 + ii * 4] = r;
  }
}

// reduce 8 partials, scale by s3, emit bf16
__global__ __launch_bounds__(256) void wfpack(
    const float* __restrict__ wfp, const float* __restrict__ s3,
    bf16_t* __restrict__ wpf)
{
  int idx = blockIdx.x * 256 + threadIdx.x;
  int o = idx >> 9;
  float s = 0.f;
  #pragma unroll
  for (int kc = 0; kc < 8; ++kc) s += wfp[(size_t)kc * 262144 + idx];
  wpf[idx] = f2bf(s * s3[o]);
}

// wp1[tap][o][i] = bf16(v1[o][i][tap] * s1[o])
__global__ __launch_bounds__(256) void wprep1(
    const float* __restrict__ v1, const float* __restrict__ s1w,
    bf16_t* __restrict__ wp)
{
  int idx = blockIdx.x * 256 + threadIdx.x;
  int i = idx & 511;
  int o = (idx >> 9) & 511;
  int tap = idx >> 18;
  wp[idx] = f2bf(v1[((size_t)o * 512 + i) * 7 + tap] * s1w[o]);
}

// fused act1d: upsample x2 (edge pad) -> snake_beta -> downsample x2
template <typename T>
__global__ __launch_bounds__(256) void act_kernel(
    const T* __restrict__ src, bf16_t* __restrict__ dst,
    const float* __restrict__ alpha, const float* __restrict__ beta,
    const float* __restrict__ filt_g)
{
  __shared__ float xs[522];
  __shared__ float ys[1034];
  __shared__ float F[12];
  int t0 = blockIdx.x * 512;
  int c = blockIdx.y;
  int b = blockIdx.z;
  const T* row = src + ((size_t)b * C_CH + c) * T_LEN;
  bf16_t* orow = dst + ((size_t)b * C_CH + c) * T_LEN;
  int tid = threadIdx.x;
  if (tid < 12) F[tid] = filt_g[tid];
  float ea = expf(alpha[c]);
  float ibv = 1.0f / (expf(beta[c]) + 1e-9f);
  for (int i = tid; i < 522; i += 256) {
    int g = t0 - 5 + i;
    g = min(max(g, 0), T_LEN - 1);
    xs[i] = loadv(row, g);
  }
  __syncthreads();
  for (int m = tid; m < 1034; m += 256) {
    int n = 2 * t0 - 5 + m;
    n = min(max(n, 0), 2 * T_LEN - 1);
    int tp = n >> 1;
    int base = tp - t0;
    float s = 0.f;
    if (n & 1) {
      #pragma unroll
      for (int u = 0; u < 6; ++u) s = fmaf(xs[base + 3 + u], F[10 - 2 * u], s);
    } else {
      #pragma unroll
      for (int u = 0; u < 6; ++u) s = fmaf(xs[base + 2 + u], F[11 - 2 * u], s);
    }
    float y = 2.f * s;
    float sn = __sinf(y * ea);
    ys[m] = fmaf(ibv * sn, sn, y);
  }
  __syncthreads();
  for (int tl = tid; tl < 512; tl += 256) {
    float h = 0.f;
    #pragma unroll
    for (int k = 0; k < 12; ++k) h = fmaf(F[k], ys[2 * tl + k], h);
    orow[t0 + tl] = f2bf(h);
  }
}

// conv K=7, 512->512, zero-pad-3, MFMA 16x16x32 bf16.
// Block: 256 threads = 4 waves (2o x 2t). Block tile 128(o) x 128(t).
// Wave tile 64x64: m4 x n4 frags (64 acc VGPRs).
// LDS: X^T tile [144 rows(t)][64 ch], 128B pitch, byte ^= (row&7)<<4 swizzle.
__global__ __launch_bounds__(256, 2) void conv7_mfma(
    const bf16_t* __restrict__ src, const bf16_t* __restrict__ wp,
    bf16_t* __restrict__ dst)
{
  __shared__ __align__(16) bf16_t Xs[144 * 64];
  const int t0 = blockIdx.x * 128;
  const int o0 = blockIdx.y * 128;
  const int b  = blockIdx.z;
  const int tid = threadIdx.x;
  const int wave = tid >> 6;
  const int wo = wave >> 1, wt = wave & 1;
  const int lane = tid & 63;
  const int l15 = lane & 15, lhi = lane >> 4;
  f32x4 acc[4][4];
  #pragma unroll
  for (int m = 0; m < 4; ++m)
    #pragma unroll
    for (int n = 0; n < 4; ++n)
      acc[m][n] = (f32x4){0.f, 0.f, 0.f, 0.f};

  const bf16_t* xg = src + (size_t)b * C_CH * T_LEN;
  const int obase = o0 + wo * 64;
  const int trow0 = wt * 64;

  for (int cb = 0; cb < 512; cb += 64) {
    for (int u = tid; u < 18 * 64; u += 256) {
      int cc = u & 63;
      int ro = u >> 6;
      int gt0 = t0 - 8 + ro * 8;
      const bf16_t* gp = xg + (size_t)(cb + cc) * T_LEN + gt0;
      bf16_t vals[8];
      if (gt0 >= 0 && gt0 + 8 <= T_LEN) {
        bf16x8 v = *(const bf16x8*)gp;
        #pragma unroll
        for (int i = 0; i < 8; ++i) vals[i] = (bf16_t)v[i];
      } else {
        #pragma unroll
        for (int i = 0; i < 8; ++i) {
          int gt = gt0 + i;
          vals[i] = (gt >= 0 && gt < T_LEN) ? gp[i] : (bf16_t)0;
        }
      }
      #pragma unroll
      for (int i = 0; i < 8; ++i) {
        int rl = ro * 8 + i;
        int byteoff = rl * 128 + ((cc * 2) ^ ((rl & 7) << 4));
        *(bf16_t*)((char*)Xs + byteoff) = vals[i];
      }
    }
    __syncthreads();
    #pragma unroll
    for (int tap = 0; tap < 7; ++tap) {
      #pragma unroll
      for (int ks = 0; ks < 2; ++ks) {
        const int chcol = ks * 32 + lhi * 8;
        bf16x8 a[4];
        #pragma unroll
        for (int m = 0; m < 4; ++m) {
          int o = obase + m * 16 + l15;
          a[m] = *(const bf16x8*)(wp + ((size_t)(tap * 512 + o) * 512) + cb + chcol);
        }
        bf16x8 bfr[4];
        #pragma unroll
        for (int n = 0; n < 4; ++n) {
          int row = trow0 + n * 16 + l15 + tap + 5;
          int byteoff = row * 128 + ((chcol * 2) ^ ((row & 7) << 4));
          bfr[n] = *(const bf16x8*)((const char*)Xs + byteoff);
        }
        #pragma unroll
        for (int m = 0; m < 4; ++m)
          #pragma unroll
          for (int n = 0; n < 4; ++n)
            acc[m][n] = __builtin_amdgcn_mfma_f32_16x16x32_bf16(a[m], bfr[n], acc[m][n], 0, 0, 0);
      }
    }
    __syncthreads();
  }
  bf16_t* drow = dst + (size_t)b * C_CH * T_LEN;
  #pragma unroll
  for (int m = 0; m < 4; ++m)
    #pragma unroll
    for (int n = 0; n < 4; ++n) {
      int t = t0 + wt * 64 + n * 16 + l15;
      #pragma unroll
      for (int r = 0; r < 4; ++r) {
        int o = obase + m * 16 + lhi * 4 + r;
        drow[(size_t)o * T_LEN + t] = f2bf(acc[m][n][r]);
      }
    }
}

// out = x + wf @ h (1x1 512->512), MFMA 16x16x32 bf16, residual f32 out
__global__ __launch_bounds__(256, 2) void gemm_mfma(
    const bf16_t* __restrict__ src, const bf16_t* __restrict__ wp,
    const float* __restrict__ x, float* __restrict__ out)
{
  __shared__ __align__(16) bf16_t Xs[128 * 64];
  const int t0 = blockIdx.x * 128;
  const int o0 = blockIdx.y * 128;
  const int b  = blockIdx.z;
  const int tid = threadIdx.x;
  const int wave = tid >> 6;
  const int wo = wave >> 1, wt = wave & 1;
  const int lane = tid & 63;
  const int l15 = lane & 15, lhi = lane >> 4;
  f32x4 acc[4][4];
  #pragma unroll
  for (int m = 0; m < 4; ++m)
    #pragma unroll
    for (int n = 0; n < 4; ++n)
      acc[m][n] = (f32x4){0.f, 0.f, 0.f, 0.f};

  const bf16_t* xg = src + (size_t)b * C_CH * T_LEN;
  const int obase = o0 + wo * 64;
  const int trow0 = wt * 64;

  for (int cb = 0; cb < 512; cb += 64) {
    for (int u = tid; u < 16 * 64; u += 256) {
      int cc = u & 63;
      int ro = u >> 6;
      const bf16_t* gp = xg + (size_t)(cb + cc) * T_LEN + t0 + ro * 8;
      bf16x8 v = *(const bf16x8*)gp;
      #pragma unroll
      for (int i = 0; i < 8; ++i) {
        int rl = ro * 8 + i;
        int byteoff = rl * 128 + ((cc * 2) ^ ((rl & 7) << 4));
        *(bf16_t*)((char*)Xs + byteoff) = (bf16_t)v[i];
      }
    }
    __syncthreads();
    #pragma unroll
    for (int ks = 0; ks < 2; ++ks) {
      const int chcol = ks * 32 + lhi * 8;
      bf16x8 a[4];
      #pragma unroll
      for (int m = 0; m < 4; ++m) {
        int o = obase + m * 16 + l15;
        a[m] = *(const bf16x8*)(wp + (size_t)o * 512 + cb + chcol);
      }
      bf16x8 bfr[4];
      #pragma unroll
      for (int n = 0; n < 4; ++n) {
        int row = trow0 + n * 16 + l15;
        int byteoff = row * 128 + ((chcol * 2) ^ ((row & 7) << 4));
        bfr[n] = *(const bf16x8*)((const char*)Xs + byteoff);
      }
      #pragma unroll
      for (int m = 0; m < 4; ++m)
        #pragma unroll
        for (int n = 0; n < 4; ++n)
          acc[m][n] = __builtin_amdgcn_mfma_f32_16x16x32_bf16(a[m], bfr[n], acc[m][n], 0, 0, 0);
    }
    __syncthreads();
  }
  #pragma unroll
  for (int m = 0; m < 4; ++m)
    #pragma unroll
    for (int n = 0; n < 4; ++n) {
      int t = t0 + wt * 64 + n * 16 + l15;
      #pragma unroll
      for (int r = 0; r < 4; ++r) {
        int o = obase + m * 16 + lhi * 4 + r;
        size_t off = ((size_t)b * C_CH + o) * T_LEN + t;
        out[off] = x[off] + acc[m][n][r];
      }
    }
}

extern "C" void kernel_launch(void* const* d_in, const int* in_sizes, int n_in,
                              void* d_out, int out_size, void* d_ws, size_t ws_size,
                              hipStream_t stream) {
  const float* x  = (const float*)d_in[0];
  const float* a1 = (const float*)d_in[1];
  const float* b1 = (const float*)d_in[2];
  const float* v1 = (const float*)d_in[3];
  const float* g1 = (const float*)d_in[4];
  const float* a2 = (const float*)d_in[5];
  const float* b2 = (const float*)d_in[6];
  const float* v2 = (const float*)d_in[7];
  const float* g2 = (const float*)d_in[8];
  const float* v3 = (const float*)d_in[9];
  const float* g3 = (const float*)d_in[10];
  float* out = (float*)d_out;
  float* ws  = (float*)d_ws;
  bf16_t* wp1 = (bf16_t*)(ws + OFF_WP1);
  bf16_t* wpf = (bf16_t*)(ws + OFF_WPF);
  bf16_t* h1  = (bf16_t*)(ws + OFF_H1);
  bf16_t* h2  = (bf16_t*)(ws + OFF_H2);
  bf16_t* h3  = (bf16_t*)(ws + OFF_H3);

  init_consts<<<3073, 256, 0, stream>>>(v1, g1, v2, g2, v3, g3, ws);
  fuse_w<<<dim3(8, 8, 8), 256, 0, stream>>>(v2, v3, ws);
  wfpack<<<1024, 256, 0, stream>>>(ws + OFF_WFP, ws + OFF_S3, wpf);
  wprep1<<<7168, 256, 0, stream>>>(v1, ws + OFF_S1, wp1);
  act_kernel<float><<<dim3(8, 512, 4), 256, 0, stream>>>(x, h1, a1, b1, ws + OFF_FILT);
  conv7_mfma<<<dim3(32, 4, 4), 256, 0, stream>>>(h1, wp1, h2);
  act_kernel<bf16_t><<<dim3(8, 512, 4), 256, 0, stream>>>(h2, h3, a2, b2, ws + OFF_FILT);
  gemm_mfma<<<dim3(32, 4, 4), 256, 0, stream>>>(h3, wpf, x, out);
}